// Round 9
// baseline (1191.511 us; speedup 1.0000x reference)
//
#include <hip/hip_runtime.h>
#include <hip/hip_bf16.h>
#include <hip/hip_cooperative_groups.h>

namespace cg = cooperative_groups;

#define N_NODES 10000
#define N_EDGES 30000
#define F_NODE  32
#define F_EDGE  8
#define EMB     64
#define HID     16
#define NGRAPH  64

#define PRE_UNITS   ((N_NODES / 8) * 4)          // 5000 (node-group x quarter)
#define EDGE_UNITS  ((N_EDGES + 255) / 256)      // 118
#define POOLZ_UNITS ((NGRAPH * EMB) / 256)       // 16
#define GAT_UNITS   (N_EDGES / 4)                // 7500
#define UPDP_UNITS  (N_NODES / 8)                // 1250

static __device__ __forceinline__ unsigned short f2bf(float f) {
    __hip_bfloat16 h = __float2bfloat16(f);
    return *(unsigned short*)&h;
}
static __device__ __forceinline__ float bf2f(unsigned short u) {
    return __uint_as_float((unsigned)u << 16);
}

// ---------- core: precompute (quarter k of 8-node group), x staged in LDS ----------
// U[n][h][o] bf16 ; XB[n,o] fp32 ; optionally zero AGGz slice for these nodes
template <int IN, bool ZAGG>
__device__ __forceinline__ void core_pre(int unit, int t,
        const float* __restrict__ xg, const float* __restrict__ w2, const float* __restrict__ b2,
        unsigned short* __restrict__ U, float* __restrict__ XB, float* __restrict__ AGGz) {
    __shared__ float xs[8][IN];
    int k = unit & 3;
    int n0 = (unit >> 2) * 8;
    __syncthreads();                                  // guard xs reuse across grid-stride units
    for (int v = t; v < 8 * IN; v += 256) xs[v / IN][v % IN] = xg[(size_t)n0 * IN + v];
    if (ZAGG && k < 2) AGGz[n0 * EMB + k * 256 + t] = 0.f;   // 512 elems via quarters 0,1
    __syncthreads();
    int h = 4 * k + (t >> 6), o = t & 63;
    const float* wrow = w2 + (size_t)h * (IN * EMB) + o;
    float acc[8];
#pragma unroll
    for (int j = 0; j < 8; j++) acc[j] = 0.f;
    for (int i = 0; i < IN; i += 4) {
        float w0 = wrow[(i + 0) * EMB];
        float w1 = wrow[(i + 1) * EMB];
        float w2v = wrow[(i + 2) * EMB];
        float w3 = wrow[(i + 3) * EMB];
#pragma unroll
        for (int j = 0; j < 8; j++) {
            acc[j] = fmaf(xs[j][i], w0, fmaf(xs[j][i + 1], w1,
                     fmaf(xs[j][i + 2], w2v, fmaf(xs[j][i + 3], w3, acc[j]))));
        }
    }
#pragma unroll
    for (int j = 0; j < 8; j++)
        U[(size_t)(n0 + j) * (HID * EMB) + h * EMB + o] = f2bf(acc[j]);
    if (t < 128) {                                    // XB cols [16k,16k+16) for 8 nodes
        int j = t >> 4, oo = k * 16 + (t & 15);
        float s = 0.f;
        for (int i = 0; i < IN; i++) s += xs[j][i] * b2[i * EMB + oo];
        XB[(n0 + j) * EMB + oo] = s;
    }
}

// ---------- core: edge MLP hidden (256 edges/unit) ----------
__device__ __forceinline__ void core_edge(int unit, int t,
        const float* __restrict__ ea,
        const float* __restrict__ w1a, const float* __restrict__ b1a,
        const float* __restrict__ w1b, const float* __restrict__ b1b,
        float* __restrict__ A0, float* __restrict__ A1) {
    int e = unit * 256 + t;
    if (e >= N_EDGES) return;
    float f[F_EDGE];
#pragma unroll
    for (int i = 0; i < F_EDGE; i++) f[i] = ea[e * F_EDGE + i];
#pragma unroll
    for (int h = 0; h < HID; h++) {
        float s0 = b1a[h], s1 = b1b[h];
#pragma unroll
        for (int i = 0; i < F_EDGE; i++) {
            s0 += f[i] * w1a[i * HID + h];
            s1 += f[i] * w1b[i * HID + h];
        }
        A0[e * HID + h] = fmaxf(s0, 0.f);
        A1[e * HID + h] = fmaxf(s1, 0.f);
    }
}

// ---------- core: gather (4 edges/unit), R5-proven U[n][h][o] access ----------
__device__ __forceinline__ void core_gather(int unit, int t,
        const float* __restrict__ A, const unsigned short* __restrict__ U,
        const float* __restrict__ XB, const int* __restrict__ src, const int* __restrict__ dst,
        float* __restrict__ AGG) {
    __shared__ float As[4][HID];
    __syncthreads();                                  // guard As reuse
    if (t < 64) As[t >> 4][t & 15] = A[(size_t)unit * 64 + t];
    __syncthreads();
    int eb = t >> 6, o = t & 63;
    int e = unit * 4 + eb;
    int s = src[e], d = dst[e];
    float m = XB[s * EMB + o];
    const unsigned short* Ue = U + (size_t)s * (HID * EMB) + o;
#pragma unroll
    for (int h = 0; h < HID; h++) m = fmaf(As[eb][h], bf2f(Ue[h * EMB]), m);
    atomicAdd(&AGG[d * EMB + o], m);
}

// ---------- core: fused update(conv k) + precompute(conv k+1), quarter-parallel ----------
// unit = group*4+quarter; update of the 8 nodes is done redundantly in all 4 quarters
// (new X kept in LDS; only quarter 0 writes Xnew to global). Zeroes AGGz (next conv's buffer).
template <int INU>
__device__ __forceinline__ void core_updpre(int unit, int t,
        const float* __restrict__ xoldg, const float* __restrict__ root, const float* __restrict__ bias,
        const float* __restrict__ AGGr, float* __restrict__ AGGz, float* __restrict__ Xnew,
        const float* __restrict__ w2, const float* __restrict__ b2,
        unsigned short* __restrict__ U, float* __restrict__ XB) {
    __shared__ float xold[8][INU];
    __shared__ float xs[8][EMB];
    int k = unit & 3;
    int n0 = (unit >> 2) * 8;
    __syncthreads();
    for (int v = t; v < 8 * INU; v += 256) xold[v / INU][v % INU] = xoldg[(size_t)n0 * INU + v];
    if (t < 128) AGGz[n0 * EMB + k * 128 + t] = 0.f;   // 512 elems over 4 quarters
    __syncthreads();
#pragma unroll
    for (int r = 0; r < 2; r++) {
        int v = t + r * 256;
        int j = v >> 6, o = v & 63;
        int n = n0 + j;
        float s = AGGr[n * EMB + o] + bias[o];
#pragma unroll
        for (int i = 0; i < INU; i++) s = fmaf(xold[j][i], root[i * EMB + o], s);
        s = fmaxf(s, 0.f);
        xs[j][o] = s;
        if (k == 0) Xnew[n * EMB + o] = s;
    }
    __syncthreads();
    // precompute next conv from LDS xs (IN = EMB)
    int h = 4 * k + (t >> 6), o = t & 63;
    const float* wrow = w2 + (size_t)h * (EMB * EMB) + o;
    float acc[8];
#pragma unroll
    for (int j = 0; j < 8; j++) acc[j] = 0.f;
    for (int i = 0; i < EMB; i += 4) {
        float w0 = wrow[(i + 0) * EMB];
        float w1 = wrow[(i + 1) * EMB];
        float w2v = wrow[(i + 2) * EMB];
        float w3 = wrow[(i + 3) * EMB];
#pragma unroll
        for (int j = 0; j < 8; j++) {
            acc[j] = fmaf(xs[j][i], w0, fmaf(xs[j][i + 1], w1,
                     fmaf(xs[j][i + 2], w2v, fmaf(xs[j][i + 3], w3, acc[j]))));
        }
    }
#pragma unroll
    for (int j = 0; j < 8; j++)
        U[(size_t)(n0 + j) * (HID * EMB) + h * EMB + o] = f2bf(acc[j]);
    if (t < 128) {
        int j = t >> 4, oo = k * 16 + (t & 15);
        float s = 0.f;
        for (int i = 0; i < EMB; i++) s += xs[j][i] * b2[i * EMB + oo];
        XB[(n0 + j) * EMB + oo] = s;
    }
}

// ---------- core: final update + max-pool (post-ReLU >= 0 -> uint atomicMax OK) ----------
__device__ __forceinline__ void core_updpool(int unit, int t,
        const float* __restrict__ xoldg, const float* __restrict__ root, const float* __restrict__ bias,
        const float* __restrict__ AGGr, const int* __restrict__ batch, unsigned* __restrict__ POOL) {
    __shared__ float xold[8][EMB];
    int n0 = unit * 8;
    __syncthreads();
    for (int v = t; v < 8 * EMB; v += 256) xold[v / EMB][v % EMB] = xoldg[(size_t)n0 * EMB + v];
    __syncthreads();
#pragma unroll
    for (int r = 0; r < 2; r++) {
        int v = t + r * 256;
        int j = v >> 6, o = v & 63;
        int n = n0 + j;
        float s = AGGr[n * EMB + o] + bias[o];
#pragma unroll
        for (int i = 0; i < EMB; i++) s = fmaf(xold[j][i], root[i * EMB + o], s);
        s = fmaxf(s, 0.f);
        atomicMax(&POOL[batch[n] * EMB + o], __float_as_uint(s));
    }
}

// ---------- core: head ----------
__device__ __forceinline__ void core_head(int t, const unsigned* __restrict__ POOL,
        const float* __restrict__ l0w, const float* __restrict__ l0b,
        const float* __restrict__ l1w, const float* __restrict__ l1b, float* __restrict__ out) {
    __shared__ float P[NGRAPH * EMB];
    for (int idx = t; idx < NGRAPH * EMB; idx += 256) P[idx] = __uint_as_float(POOL[idx]);
    __syncthreads();
    if (t < NGRAPH) {
        int g = t;
        float acc = l1b[0];
        for (int o2 = 0; o2 < EMB; o2++) {
            float h = l0b[o2];
            for (int o = 0; o < EMB; o++) h += P[g * EMB + o] * l0w[o * EMB + o2];
            acc += h * l1w[o2];
        }
        out[g] = acc;
    }
}

// =================== parameter block ===================
struct MP {
    const float *x_p, *ea;
    const int *src, *dst, *batch;
    const float *nn0_w1, *nn0_b1, *nn0_w2, *nn0_b2;
    const float *nn1_w1, *nn1_b1, *nn1_w2, *nn1_b2;
    const float *root0, *bias0, *root1, *bias1, *root2, *bias2;
    const float *lin0_w, *lin0_b, *lin1_w, *lin1_b;
    float *A0, *A1;
    unsigned short *U;
    float *XB, *X1, *X2, *AGGa, *AGGb;
    unsigned *POOL;
    float *out;
};

// =================== cooperative megakernel ===================
__global__ void __launch_bounds__(256, 4) mega(MP p) {
    cg::grid_group grid = cg::this_grid();
    const int t = threadIdx.x;
    const int G = gridDim.x;
    // A: pre conv0 + edge MLP + POOL zero (+ AGGa zero inside pre)
    for (int u = blockIdx.x; u < PRE_UNITS + EDGE_UNITS + POOLZ_UNITS; u += G) {
        if (u < PRE_UNITS) core_pre<F_NODE, true>(u, t, p.x_p, p.nn0_w2, p.nn0_b2, p.U, p.XB, p.AGGa);
        else if (u < PRE_UNITS + EDGE_UNITS)
            core_edge(u - PRE_UNITS, t, p.ea, p.nn0_w1, p.nn0_b1, p.nn1_w1, p.nn1_b1, p.A0, p.A1);
        else p.POOL[(u - PRE_UNITS - EDGE_UNITS) * 256 + t] = 0u;
    }
    grid.sync();
    for (int u = blockIdx.x; u < GAT_UNITS; u += G) core_gather(u, t, p.A0, p.U, p.XB, p.src, p.dst, p.AGGa);
    grid.sync();
    for (int u = blockIdx.x; u < PRE_UNITS; u += G)
        core_updpre<F_NODE>(u, t, p.x_p, p.root0, p.bias0, p.AGGa, p.AGGb, p.X1, p.nn1_w2, p.nn1_b2, p.U, p.XB);
    grid.sync();
    for (int u = blockIdx.x; u < GAT_UNITS; u += G) core_gather(u, t, p.A1, p.U, p.XB, p.src, p.dst, p.AGGb);
    grid.sync();
    for (int u = blockIdx.x; u < PRE_UNITS; u += G)
        core_updpre<EMB>(u, t, p.X1, p.root1, p.bias1, p.AGGb, p.AGGa, p.X2, p.nn1_w2, p.nn1_b2, p.U, p.XB);
    grid.sync();
    for (int u = blockIdx.x; u < GAT_UNITS; u += G) core_gather(u, t, p.A1, p.U, p.XB, p.src, p.dst, p.AGGa);
    grid.sync();
    for (int u = blockIdx.x; u < UPDP_UNITS; u += G)
        core_updpool(u, t, p.X2, p.root2, p.bias2, p.AGGa, p.batch, p.POOL);
    grid.sync();
    if (blockIdx.x == 0) core_head(t, p.POOL, p.lin0_w, p.lin0_b, p.lin1_w, p.lin1_b, p.out);
}

// =================== split-kernel fallback ===================
__global__ void __launch_bounds__(256) k_pre0(MP p) {
    int b = blockIdx.x, t = threadIdx.x;
    if (b < PRE_UNITS) core_pre<F_NODE, true>(b, t, p.x_p, p.nn0_w2, p.nn0_b2, p.U, p.XB, p.AGGa);
    else if (b < PRE_UNITS + EDGE_UNITS)
        core_edge(b - PRE_UNITS, t, p.ea, p.nn0_w1, p.nn0_b1, p.nn1_w1, p.nn1_b1, p.A0, p.A1);
    else p.POOL[(b - PRE_UNITS - EDGE_UNITS) * 256 + t] = 0u;
}
__global__ void __launch_bounds__(256) k_gath(MP p, const float* A, float* AGG) {
    core_gather(blockIdx.x, threadIdx.x, A, p.U, p.XB, p.src, p.dst, AGG);
}
template <int INU>
__global__ void __launch_bounds__(256) k_updpre(MP p, const float* xold, const float* root,
        const float* bias, const float* AGGr, float* AGGz, float* Xnew) {
    core_updpre<INU>(blockIdx.x, threadIdx.x, xold, root, bias, AGGr, AGGz, Xnew,
                     p.nn1_w2, p.nn1_b2, p.U, p.XB);
}
__global__ void __launch_bounds__(256) k_updpool(MP p) {
    core_updpool(blockIdx.x, threadIdx.x, p.X2, p.root2, p.bias2, p.AGGa, p.batch, p.POOL);
}
__global__ void __launch_bounds__(256) k_head(MP p) {
    core_head(threadIdx.x, p.POOL, p.lin0_w, p.lin0_b, p.lin1_w, p.lin1_b, p.out);
}

extern "C" void kernel_launch(void* const* d_in, const int* in_sizes, int n_in,
                              void* d_out, int out_size, void* d_ws, size_t ws_size,
                              hipStream_t stream) {
    MP p;
    p.x_p    = (const float*)d_in[0];
    p.ea     = (const float*)d_in[2];
    const int* eidx = (const int*)d_in[4];
    p.src    = eidx;
    p.dst    = eidx + N_EDGES;
    p.batch  = (const int*)d_in[5];
    p.nn0_w1 = (const float*)d_in[6];  p.nn0_b1 = (const float*)d_in[7];
    p.nn0_w2 = (const float*)d_in[8];  p.nn0_b2 = (const float*)d_in[9];
    p.nn1_w1 = (const float*)d_in[10]; p.nn1_b1 = (const float*)d_in[11];
    p.nn1_w2 = (const float*)d_in[12]; p.nn1_b2 = (const float*)d_in[13];
    p.root0  = (const float*)d_in[14]; p.bias0  = (const float*)d_in[15];
    p.root1  = (const float*)d_in[16]; p.bias1  = (const float*)d_in[17];
    p.root2  = (const float*)d_in[18]; p.bias2  = (const float*)d_in[19];
    p.lin0_w = (const float*)d_in[20]; p.lin0_b = (const float*)d_in[21];
    p.lin1_w = (const float*)d_in[22]; p.lin1_b = (const float*)d_in[23];

    char* ws = (char*)d_ws;
    p.A0   = (float*)ws;          ws += (size_t)N_EDGES * HID * 4;
    p.A1   = (float*)ws;          ws += (size_t)N_EDGES * HID * 4;
    p.U    = (unsigned short*)ws; ws += (size_t)N_NODES * HID * EMB * 2;   // [n][h][o]
    p.XB   = (float*)ws;          ws += (size_t)N_NODES * EMB * 4;
    p.X1   = (float*)ws;          ws += (size_t)N_NODES * EMB * 4;
    p.X2   = (float*)ws;          ws += (size_t)N_NODES * EMB * 4;
    p.AGGa = (float*)ws;          ws += (size_t)N_NODES * EMB * 4;
    p.AGGb = (float*)ws;          ws += (size_t)N_NODES * EMB * 4;
    p.POOL = (unsigned*)ws;       ws += (size_t)NGRAPH * EMB * 4;
    p.out  = (float*)d_out;

    // ---- try cooperative megakernel (guarded), else split launches ----
    bool coop_done = false;
    int coopAttr = 0, dev = 0, nCU = 0, maxBlk = 0;
    if (hipGetDevice(&dev) == hipSuccess &&
        hipDeviceGetAttribute(&coopAttr, hipDeviceAttributeCooperativeLaunch, dev) == hipSuccess &&
        coopAttr &&
        hipDeviceGetAttribute(&nCU, hipDeviceAttributeMultiprocessorCount, dev) == hipSuccess &&
        hipOccupancyMaxActiveBlocksPerMultiprocessor(&maxBlk, (const void*)mega, 256, 0) == hipSuccess &&
        maxBlk >= 1 && nCU >= 1) {
        int nblk = maxBlk * nCU;
        if (nblk > 1024) nblk = 1024;
        if (nblk >= 512) {
            void* args[] = { &p };
            if (hipLaunchCooperativeKernel((void*)mega, dim3(nblk), dim3(256), args, 0, stream)
                    == hipSuccess) {
                coop_done = true;
            } else {
                (void)hipGetLastError();   // clear sticky error, fall through to split path
            }
        }
    }
    if (!coop_done) {
        k_pre0<<<PRE_UNITS + EDGE_UNITS + POOLZ_UNITS, 256, 0, stream>>>(p);
        k_gath<<<GAT_UNITS, 256, 0, stream>>>(p, p.A0, p.AGGa);
        k_updpre<F_NODE><<<PRE_UNITS, 256, 0, stream>>>(p, p.x_p, p.root0, p.bias0, p.AGGa, p.AGGb, p.X1);
        k_gath<<<GAT_UNITS, 256, 0, stream>>>(p, p.A1, p.AGGb);
        k_updpre<EMB><<<PRE_UNITS, 256, 0, stream>>>(p, p.X1, p.root1, p.bias1, p.AGGb, p.AGGa, p.X2);
        k_gath<<<GAT_UNITS, 256, 0, stream>>>(p, p.A1, p.AGGa);
        k_updpool<<<UPDP_UNITS, 256, 0, stream>>>(p);
        k_head<<<1, 256, 0, stream>>>(p);
    }
}

// Round 10
// 279.868 us; speedup vs baseline: 4.2574x; 4.2574x over previous
//
#include <hip/hip_runtime.h>
#include <hip/hip_bf16.h>

#define N_NODES 10000
#define N_EDGES 30000
#define F_NODE  32
#define F_EDGE  8
#define EMB     64
#define HID     16
#define NGRAPH  64

#define PRE_UNITS   ((N_NODES / 8) * 4)          // 5000 (node-group x quarter)
#define EDGE_UNITS  ((N_EDGES + 255) / 256)      // 118
#define POOLZ_UNITS ((NGRAPH * EMB) / 256)       // 16
#define GAT_GRID    (N_EDGES / 4)                // 7500
#define UPDP_GRID   (N_NODES / 8)                // 1250

static __device__ __forceinline__ unsigned short f2bf(float f) {
    __hip_bfloat16 h = __float2bfloat16(f);
    return *(unsigned short*)&h;
}
static __device__ __forceinline__ float bf2f(unsigned short u) {
    return __uint_as_float((unsigned)u << 16);
}

// =================== parameter block ===================
struct MP {
    const float *x_p, *ea;
    const int *src, *dst, *batch;
    const float *nn0_w1, *nn0_b1, *nn0_w2, *nn0_b2;
    const float *nn1_w1, *nn1_b1, *nn1_w2, *nn1_b2;
    const float *root0, *bias0, *root1, *bias1, *root2, *bias2;
    const float *lin0_w, *lin0_b, *lin1_w, *lin1_b;
    float *A0, *A1;
    unsigned short *U;       // [n][h][o] bf16
    float *XB, *X1, *X2, *AGGa, *AGGb;
    unsigned *POOL;
    float *out;
};

// ---- kernel 1: pre conv0 (units 0..4999: group*4+quarter) + edge MLP + POOL zero.
//      U[n][h][o] = sum_i x[n,i]*w2[h,i*EMB+o] (bf16), XB[n,o] = sum_i x[n,i]*b2[i*EMB+o].
//      Quarters 0,1 of each group also zero AGGa's 512-float slice.
__global__ void __launch_bounds__(256) k_pre0(MP p) {
    int b = blockIdx.x, t = threadIdx.x;
    if (b < PRE_UNITS) {
        __shared__ float xs[8][F_NODE];
        int k = b & 3;
        int n0 = (b >> 2) * 8;
        for (int v = t; v < 8 * F_NODE; v += 256) xs[v / F_NODE][v % F_NODE] = p.x_p[(size_t)n0 * F_NODE + v];
        if (k < 2) p.AGGa[n0 * EMB + k * 256 + t] = 0.f;
        __syncthreads();
        int h = 4 * k + (t >> 6), o = t & 63;
        const float* wrow = p.nn0_w2 + (size_t)h * (F_NODE * EMB) + o;
        float acc[8];
#pragma unroll
        for (int j = 0; j < 8; j++) acc[j] = 0.f;
        for (int i = 0; i < F_NODE; i += 4) {
            float w0 = wrow[(i + 0) * EMB];
            float w1 = wrow[(i + 1) * EMB];
            float w2v = wrow[(i + 2) * EMB];
            float w3 = wrow[(i + 3) * EMB];
#pragma unroll
            for (int j = 0; j < 8; j++)
                acc[j] = fmaf(xs[j][i], w0, fmaf(xs[j][i + 1], w1,
                         fmaf(xs[j][i + 2], w2v, fmaf(xs[j][i + 3], w3, acc[j]))));
        }
#pragma unroll
        for (int j = 0; j < 8; j++)
            p.U[(size_t)(n0 + j) * (HID * EMB) + h * EMB + o] = f2bf(acc[j]);
        if (t < 128) {
            int j = t >> 4, oo = k * 16 + (t & 15);
            float s = 0.f;
            for (int i = 0; i < F_NODE; i++) s += xs[j][i] * p.nn0_b2[i * EMB + oo];
            p.XB[(n0 + j) * EMB + oo] = s;
        }
    } else if (b < PRE_UNITS + EDGE_UNITS) {
        int e = (b - PRE_UNITS) * 256 + t;
        if (e >= N_EDGES) return;
        float f[F_EDGE];
#pragma unroll
        for (int i = 0; i < F_EDGE; i++) f[i] = p.ea[e * F_EDGE + i];
#pragma unroll
        for (int h = 0; h < HID; h++) {
            float s0 = p.nn0_b1[h], s1 = p.nn1_b1[h];
#pragma unroll
            for (int i = 0; i < F_EDGE; i++) {
                s0 += f[i] * p.nn0_w1[i * HID + h];
                s1 += f[i] * p.nn1_w1[i * HID + h];
            }
            p.A0[e * HID + h] = fmaxf(s0, 0.f);
            p.A1[e * HID + h] = fmaxf(s1, 0.f);
        }
    } else {
        p.POOL[(b - PRE_UNITS - EDGE_UNITS) * 256 + t] = 0u;
    }
}

// ---- gather: 4 edges/block; msg[e,o] = XB[src,o] + sum_h A[e,h]*U[src][h][o]; atomicAdd AGG[dst,o]
__global__ void __launch_bounds__(256) k_gath(MP p, const float* __restrict__ A,
                                              float* __restrict__ AGG) {
    __shared__ float As[4][HID];
    int t = threadIdx.x;
    if (t < 64) As[t >> 4][t & 15] = A[(size_t)blockIdx.x * 64 + t];
    __syncthreads();
    int eb = t >> 6, o = t & 63;
    int e = blockIdx.x * 4 + eb;               // 30000/4 = 7500 exact
    int s = p.src[e], d = p.dst[e];
    float m = p.XB[s * EMB + o];
    const unsigned short* Ue = p.U + (size_t)s * (HID * EMB) + o;
    const float* Ae = As[eb];
#pragma unroll
    for (int h = 0; h < HID; h++) m = fmaf(Ae[h], bf2f(Ue[h * EMB]), m);
    atomicAdd(&AGG[d * EMB + o], m);
}

// ---- fused update(conv k)+pre(conv k+1), quarter-parallel (5000 blocks).
//      All 4 quarters of a group redundantly compute the 8-node update into LDS;
//      quarter 0 writes Xnew to global; each quarter then computes its own U/XB slice.
//      Also zeroes AGGz (the NEXT conv's accumulation buffer — ping-pong, no race).
template <int INU>
__global__ void __launch_bounds__(256) k_updpre(MP p, const float* __restrict__ xoldg,
        const float* __restrict__ root, const float* __restrict__ bias,
        const float* __restrict__ AGGr, float* __restrict__ AGGz, float* __restrict__ Xnew) {
    __shared__ float xold[8][INU];
    __shared__ float xs[8][EMB];
    int k = blockIdx.x & 3;
    int n0 = (blockIdx.x >> 2) * 8;
    int t = threadIdx.x;
    for (int v = t; v < 8 * INU; v += 256) xold[v / INU][v % INU] = xoldg[(size_t)n0 * INU + v];
    if (t < 128) AGGz[n0 * EMB + k * 128 + t] = 0.f;        // 512 floats over 4 quarters
    __syncthreads();
#pragma unroll
    for (int r = 0; r < 2; r++) {
        int v = t + r * 256;
        int j = v >> 6, o = v & 63;
        int n = n0 + j;
        float s = AGGr[n * EMB + o] + bias[o];
#pragma unroll
        for (int i = 0; i < INU; i++) s = fmaf(xold[j][i], root[i * EMB + o], s);
        s = fmaxf(s, 0.f);
        xs[j][o] = s;
        if (k == 0) Xnew[n * EMB + o] = s;
    }
    __syncthreads();
    int h = 4 * k + (t >> 6), o = t & 63;
    const float* wrow = p.nn1_w2 + (size_t)h * (EMB * EMB) + o;
    float acc[8];
#pragma unroll
    for (int j = 0; j < 8; j++) acc[j] = 0.f;
    for (int i = 0; i < EMB; i += 4) {
        float w0 = wrow[(i + 0) * EMB];
        float w1 = wrow[(i + 1) * EMB];
        float w2v = wrow[(i + 2) * EMB];
        float w3 = wrow[(i + 3) * EMB];
#pragma unroll
        for (int j = 0; j < 8; j++)
            acc[j] = fmaf(xs[j][i], w0, fmaf(xs[j][i + 1], w1,
                     fmaf(xs[j][i + 2], w2v, fmaf(xs[j][i + 3], w3, acc[j]))));
    }
#pragma unroll
    for (int j = 0; j < 8; j++)
        p.U[(size_t)(n0 + j) * (HID * EMB) + h * EMB + o] = f2bf(acc[j]);
    if (t < 128) {
        int j = t >> 4, oo = k * 16 + (t & 15);
        float s = 0.f;
        for (int i = 0; i < EMB; i++) s += xs[j][i] * p.nn1_b2[i * EMB + oo];
        p.XB[(n0 + j) * EMB + oo] = s;
    }
}

// ---- final update + max-pool (post-ReLU >= 0: uint atomicMax is order-preserving)
__global__ void __launch_bounds__(256) k_updpool(MP p) {
    __shared__ float xold[8][EMB];
    int n0 = blockIdx.x * 8;
    int t = threadIdx.x;
    for (int v = t; v < 8 * EMB; v += 256) xold[v / EMB][v % EMB] = p.X2[(size_t)n0 * EMB + v];
    __syncthreads();
#pragma unroll
    for (int r = 0; r < 2; r++) {
        int v = t + r * 256;
        int j = v >> 6, o = v & 63;
        int n = n0 + j;
        float s = p.AGGa[n * EMB + o] + p.bias2[o];
#pragma unroll
        for (int i = 0; i < EMB; i++) s = fmaf(xold[j][i], p.root2[i * EMB + o], s);
        s = fmaxf(s, 0.f);
        atomicMax(&p.POOL[p.batch[n] * EMB + o], __float_as_uint(s));
    }
}

// ---- head: out[g] = (pooled[g]@lin0_w + lin0_b) @ lin1_w + lin1_b
__global__ void __launch_bounds__(256) k_head(MP p) {
    __shared__ float P[NGRAPH * EMB];
    int t = threadIdx.x;
    for (int idx = t; idx < NGRAPH * EMB; idx += 256) P[idx] = __uint_as_float(p.POOL[idx]);
    __syncthreads();
    if (t < NGRAPH) {
        int g = t;
        float acc = p.lin1_b[0];
        for (int o2 = 0; o2 < EMB; o2++) {
            float h = p.lin0_b[o2];
            for (int o = 0; o < EMB; o++) h += P[g * EMB + o] * p.lin0_w[o * EMB + o2];
            acc += h * p.lin1_w[o2];
        }
        p.out[g] = acc;
    }
}

extern "C" void kernel_launch(void* const* d_in, const int* in_sizes, int n_in,
                              void* d_out, int out_size, void* d_ws, size_t ws_size,
                              hipStream_t stream) {
    MP p;
    p.x_p    = (const float*)d_in[0];
    p.ea     = (const float*)d_in[2];
    const int* eidx = (const int*)d_in[4];
    p.src    = eidx;
    p.dst    = eidx + N_EDGES;
    p.batch  = (const int*)d_in[5];
    p.nn0_w1 = (const float*)d_in[6];  p.nn0_b1 = (const float*)d_in[7];
    p.nn0_w2 = (const float*)d_in[8];  p.nn0_b2 = (const float*)d_in[9];
    p.nn1_w1 = (const float*)d_in[10]; p.nn1_b1 = (const float*)d_in[11];
    p.nn1_w2 = (const float*)d_in[12]; p.nn1_b2 = (const float*)d_in[13];
    p.root0  = (const float*)d_in[14]; p.bias0  = (const float*)d_in[15];
    p.root1  = (const float*)d_in[16]; p.bias1  = (const float*)d_in[17];
    p.root2  = (const float*)d_in[18]; p.bias2  = (const float*)d_in[19];
    p.lin0_w = (const float*)d_in[20]; p.lin0_b = (const float*)d_in[21];
    p.lin1_w = (const float*)d_in[22]; p.lin1_b = (const float*)d_in[23];

    char* ws = (char*)d_ws;
    p.A0   = (float*)ws;          ws += (size_t)N_EDGES * HID * 4;
    p.A1   = (float*)ws;          ws += (size_t)N_EDGES * HID * 4;
    p.U    = (unsigned short*)ws; ws += (size_t)N_NODES * HID * EMB * 2;   // [n][h][o]
    p.XB   = (float*)ws;          ws += (size_t)N_NODES * EMB * 4;
    p.X1   = (float*)ws;          ws += (size_t)N_NODES * EMB * 4;
    p.X2   = (float*)ws;          ws += (size_t)N_NODES * EMB * 4;
    p.AGGa = (float*)ws;          ws += (size_t)N_NODES * EMB * 4;
    p.AGGb = (float*)ws;          ws += (size_t)N_NODES * EMB * 4;
    p.POOL = (unsigned*)ws;       ws += (size_t)NGRAPH * EMB * 4;
    p.out  = (float*)d_out;

    // 1: pre conv0 + edge MLPs + AGGa/POOL zeroing
    k_pre0<<<PRE_UNITS + EDGE_UNITS + POOLZ_UNITS, 256, 0, stream>>>(p);
    // 2: gather conv0 -> AGGa
    k_gath<<<GAT_GRID, 256, 0, stream>>>(p, p.A0, p.AGGa);
    // 3: update conv0 (AGGa) + pre conv1 ; zero AGGb ; X1 = new features
    k_updpre<F_NODE><<<PRE_UNITS, 256, 0, stream>>>(p, p.x_p, p.root0, p.bias0, p.AGGa, p.AGGb, p.X1);
    // 4: gather conv1 -> AGGb
    k_gath<<<GAT_GRID, 256, 0, stream>>>(p, p.A1, p.AGGb);
    // 5: update conv1 (AGGb) + pre conv2 ; zero AGGa ; X2
    k_updpre<EMB><<<PRE_UNITS, 256, 0, stream>>>(p, p.X1, p.root1, p.bias1, p.AGGb, p.AGGa, p.X2);
    // 6: gather conv2 -> AGGa
    k_gath<<<GAT_GRID, 256, 0, stream>>>(p, p.A1, p.AGGa);
    // 7: update conv2 + max-pool
    k_updpool<<<UPDP_GRID, 256, 0, stream>>>(p);
    // 8: head
    k_head<<<1, 256, 0, stream>>>(p);
}